// Round 13
// baseline (154.868 us; speedup 1.0000x reference)
//
#include <hip/hip_runtime.h>
#include <hip/hip_fp16.h>
#include <math.h>

#define IN_C 128
#define HC   128
#define OUT_C 64
#define NEG_SLOPE 0.2f
#define LN_EPS 1e-5f
#define CHUNK 4096        // edges per partition chunk (391 chunks)
#define BSH   8           // bucket shift: 256 nodes per bucket
#define BMSK  255
#define NBMAX 512         // max buckets (dst>>8; M<=131072)
#define NB2MAX 1024       // max scan blocks (4/thread inline scan)
#define NGB   391         // persistent gemm blocks (1563 tiles / 391 ~= 4)

typedef __attribute__((ext_vector_type(8))) short bf16x8;
typedef __attribute__((ext_vector_type(4))) float f32x4;

// round-to-nearest-even bf16 pack of two floats -> uint (a=low, b=high)
__device__ inline unsigned bf16pack(float a, float b) {
    unsigned ua = __float_as_uint(a), ub = __float_as_uint(b);
    ua = (ua + 0x7fffu + ((ua >> 16) & 1u)) >> 16;
    ub = (ub + 0x7fffu + ((ub >> 16) & 1u)) >> 16;
    return ua | (ub << 16);
}

// ---------------------------------------------------------------------------
// A: blocks 0..7 WbfT[col][k]=bf16(W[k][col]); block 8 folds V; blocks 9..
// per-chunk LDS histogram over NB buckets -> off[bucket][chunk] raw counts.
// ---------------------------------------------------------------------------
__global__ __launch_bounds__(256) void k_pre(const float* __restrict__ W,
                                             const float* __restrict__ W_edge,
                                             const float* __restrict__ att_edge,
                                             const int* __restrict__ ei_dst,
                                             unsigned short* __restrict__ WbfT,
                                             float* __restrict__ V,
                                             int* __restrict__ off,
                                             int E, int NB, int PB) {
    __shared__ int hist[NBMAX];
    int b = blockIdx.x, t = threadIdx.x;
    if (b < 8) {
        #pragma unroll
        for (int i = 0; i < 8; ++i) {
            int idx = b * 2048 + i * 256 + t;      // 0..16383
            int k = idx >> 7, col = idx & 127;
            unsigned u = __float_as_uint(W[idx]);
            WbfT[col * 128 + k] =
                (unsigned short)((u + 0x7fffu + ((u >> 16) & 1u)) >> 16);
        }
        return;
    }
    if (b == 8) {
        if (t < 8) {
            int d = t >> 1, h = t & 1;
            float s = 0.f;
            for (int c = 0; c < 64; ++c)
                s += W_edge[d * HC + h * 64 + c] * att_edge[h * 64 + c];
            V[d * 2 + h] = s;
        }
        return;
    }
    int pb = b - 9;
    for (int i = t; i < NB; i += 256) hist[i] = 0;
    __syncthreads();
    int base = pb * CHUNK;
    int lim = E - base; if (lim > CHUNK) lim = CHUNK;
    if (lim == CHUNK) {                       // 16 edges/thread, 4x int4
        #pragma unroll
        for (int u = 0; u < 4; ++u) {
            int4 v = *(const int4*)&ei_dst[base + u * 1024 + t * 4];
            atomicAdd(&hist[v.x >> BSH], 1);
            atomicAdd(&hist[v.y >> BSH], 1);
            atomicAdd(&hist[v.z >> BSH], 1);
            atomicAdd(&hist[v.w >> BSH], 1);
        }
    } else {
        for (int i = t; i < lim; i += 256)
            atomicAdd(&hist[ei_dst[base + i] >> BSH], 1);
    }
    __syncthreads();
    for (int i = t; i < NB; i += 256)
        off[(size_t)i * PB + pb] = hist[i];
}

// ---------------------------------------------------------------------------
// B: scan1 of off[] (1024 elems/block, in-place exclusive; raw bsum out)
// ---------------------------------------------------------------------------
__global__ __launch_bounds__(256) void k_scan(int* __restrict__ off,
                                              int* __restrict__ bsum, int nS) {
    __shared__ int sm[256];
    int t = threadIdx.x;
    int base = blockIdx.x * 1024 + t * 4;
    int v0 = 0, v1 = 0, v2 = 0, v3 = 0;
    if (base + 0 < nS) v0 = off[base + 0];
    if (base + 1 < nS) v1 = off[base + 1];
    if (base + 2 < nS) v2 = off[base + 2];
    if (base + 3 < nS) v3 = off[base + 3];
    int s = v0 + v1 + v2 + v3;
    sm[t] = s;
    __syncthreads();
    for (int o = 1; o < 256; o <<= 1) {
        int u = (t >= o) ? sm[t - o] : 0;
        __syncthreads();
        sm[t] += u;
        __syncthreads();
    }
    int excl = sm[t] - s;
    if (base + 0 < nS) off[base + 0] = excl;
    if (base + 1 < nS) off[base + 1] = excl + v0;
    if (base + 2 < nS) off[base + 2] = excl + v0 + v1;
    if (base + 3 < nS) off[base + 3] = excl + v0 + v1 + v2;
    if (t == 255) bsum[blockIdx.x] = sm[255];
}

// ---------------------------------------------------------------------------
// inline exclusive scan of bsum[0..nb2) into bs[] (nb2 <= 1024, 4/thread)
// ---------------------------------------------------------------------------
__device__ inline void scan_bsum(const int* __restrict__ bsum, int nb2,
                                 int* bs, int* sm, int t) {
    int v0 = (4 * t + 0 < nb2) ? bsum[4 * t + 0] : 0;
    int v1 = (4 * t + 1 < nb2) ? bsum[4 * t + 1] : 0;
    int v2 = (4 * t + 2 < nb2) ? bsum[4 * t + 2] : 0;
    int v3 = (4 * t + 3 < nb2) ? bsum[4 * t + 3] : 0;
    int s = v0 + v1 + v2 + v3;
    sm[t] = s;
    __syncthreads();
    for (int o = 1; o < 256; o <<= 1) {
        int u = (t >= o) ? sm[t - o] : 0;
        __syncthreads();
        sm[t] += u;
        __syncthreads();
    }
    int excl = sm[t] - s;
    bs[4 * t + 0] = excl;
    bs[4 * t + 1] = excl + v0;
    bs[4 * t + 2] = excl + v0 + v1;
    bs[4 * t + 3] = excl + v0 + v1 + v2;
    __syncthreads();
}

// ---------------------------------------------------------------------------
// C: partition scatter (no alpha): ae = ea.V only.
// pA = {src | dl<<17, half2(ae0,ae1)}; chunk 0 publishes scanned bsum2.
// ---------------------------------------------------------------------------
__global__ __launch_bounds__(256) void k_part(const int* __restrict__ ei,
                                              const float* __restrict__ ea,
                                              const float* __restrict__ V,
                                              const int* __restrict__ off,
                                              const int* __restrict__ bsum,
                                              int* __restrict__ bsum2,
                                              uint2* __restrict__ pA,
                                              int E, int NB, int PB, int nb2) {
    __shared__ int cur[NBMAX];
    __shared__ int bs[NB2MAX];
    __shared__ int sm[256];
    int pb = blockIdx.x, t = threadIdx.x;

    scan_bsum(bsum, nb2, bs, sm, t);
    if (pb == 0)
        for (int i = t; i < nb2; i += 256) bsum2[i] = bs[i];

    for (int i = t; i < NB; i += 256) {
        size_t oi = (size_t)i * PB + pb;
        cur[i] = off[oi] + bs[(int)(oi >> 10)];
    }
    __syncthreads();
    float v0 = V[0], v1 = V[1], v2 = V[2], v3 = V[3];
    float v4 = V[4], v5 = V[5], v6 = V[6], v7 = V[7];
    int base = pb * CHUNK;
    int lim = E - base; if (lim > CHUNK) lim = CHUNK;
    if (lim == CHUNK) {                       // 2 batches x 8 edges/thread
        #pragma unroll
        for (int h = 0; h < 2; ++h) {
            int e0 = base + h * 2048 + t;
            int sA[8], dA[8];
            #pragma unroll
            for (int k = 0; k < 8; ++k) {
                sA[k] = ei[e0 + k * 256];
                dA[k] = ei[E + e0 + k * 256];
            }
            float4 aA[8];
            #pragma unroll
            for (int k = 0; k < 8; ++k)
                aA[k] = ((const float4*)ea)[e0 + k * 256];
            #pragma unroll
            for (int k = 0; k < 8; ++k) {
                float ae0 = aA[k].x * v0 + aA[k].y * v2 + aA[k].z * v4 + aA[k].w * v6;
                float ae1 = aA[k].x * v1 + aA[k].y * v3 + aA[k].z * v5 + aA[k].w * v7;
                __half2 hx = __floats2half2_rn(ae0, ae1);
                int slot = atomicAdd(&cur[dA[k] >> BSH], 1);
                pA[slot] = make_uint2(
                    (unsigned)sA[k] | ((unsigned)(dA[k] & BMSK) << 17),
                    *reinterpret_cast<unsigned*>(&hx));
            }
        }
    } else {
        for (int i = t; i < lim; i += 256) {
            int e = base + i;
            int s = ei[e], d = ei[E + e];
            float4 a = ((const float4*)ea)[e];
            float ae0 = a.x * v0 + a.y * v2 + a.z * v4 + a.w * v6;
            float ae1 = a.x * v1 + a.y * v3 + a.z * v5 + a.w * v7;
            __half2 hx = __floats2half2_rn(ae0, ae1);
            int slot = atomicAdd(&cur[d >> BSH], 1);
            pA[slot] = make_uint2((unsigned)s | ((unsigned)(d & BMSK) << 17),
                                  *reinterpret_cast<unsigned*>(&hx));
        }
    }
}

// ---------------------------------------------------------------------------
// D: MFMA GEMM, grid-stride persistent blocks with DOUBLE-BUFFERED LDS:
// issue next tile's global loads BEFORE computing current tile, so HBM
// latency hides under MFMA + epilogue. 391 blocks x ~4 tiles.
// ---------------------------------------------------------------------------
__global__ __launch_bounds__(256) void k_gemm(const float* __restrict__ x,
                                              const unsigned short* __restrict__ WbfT,
                                              const float* __restrict__ attS,
                                              const float* __restrict__ attD,
                                              unsigned* __restrict__ hb,
                                              float* __restrict__ a_src,
                                              float* __restrict__ a_dst,
                                              int M, int T, int stride) {
    __shared__ unsigned xb[2][64 * 64];       // 2 x 16 KB
    const int t = threadIdx.x;
    const float4* x4 = (const float4*)x;
    const int w = t >> 6, lane = t & 63;
    const int col = lane & 15, qr = lane >> 4;
    const int srow = t >> 5, sc4 = t & 31;    // staging row/col4 (8 rows apart)

    float sv[8], dv[8];
    #pragma unroll
    for (int ct = 0; ct < 8; ++ct) {
        sv[ct] = attS[ct * 16 + col];
        dv[ct] = attD[ct * 16 + col];
    }

    auto LOAD = [&](int tile, float4* lr) {
        int brow = tile * 64;
        #pragma unroll
        for (int i = 0; i < 8; ++i) {
            int row = brow + srow + i * 8;
            lr[i] = (row < M) ? x4[(size_t)row * 32 + sc4]
                              : make_float4(0.f, 0.f, 0.f, 0.f);
        }
    };
    auto STORE = [&](int buf, const float4* lr) {
        #pragma unroll
        for (int i = 0; i < 8; ++i) {
            int row = srow + i * 8;
            unsigned lo = bf16pack(lr[i].x, lr[i].y);
            unsigned hi = bf16pack(lr[i].z, lr[i].w);
            int byte = row * 256 + ((sc4 * 8) ^ ((row & 7) << 4));
            *(uint2*)((char*)xb[buf] + byte) = make_uint2(lo, hi);
        }
    };
    auto COMPUTE = [&](int buf, int tile) {
        const int brow = tile * 64;
        f32x4 acc[8];
        #pragma unroll
        for (int ct = 0; ct < 8; ++ct) acc[ct] = (f32x4){0.f, 0.f, 0.f, 0.f};
        const int arow = w * 16 + col;
        #pragma unroll
        for (int ks = 0; ks < 4; ++ks) {
            int abyte = arow * 256 + ((ks * 64 + qr * 16) ^ ((arow & 7) << 4));
            bf16x8 af = *(const bf16x8*)((const char*)xb[buf] + abyte);
            #pragma unroll
            for (int ct = 0; ct < 8; ++ct) {
                bf16x8 bfr = *(const bf16x8*)&WbfT[(size_t)(ct * 16 + col) * 128 + ks * 32 + qr * 8];
                acc[ct] = __builtin_amdgcn_mfma_f32_16x16x32_bf16(af, bfr, acc[ct], 0, 0, 0);
            }
        }
        float pS0[4], pS1[4], pD0[4], pD1[4];
        #pragma unroll
        for (int r = 0; r < 4; ++r) { pS0[r] = pS1[r] = pD0[r] = pD1[r] = 0.f; }
        #pragma unroll
        for (int ct = 0; ct < 8; ++ct) {
            #pragma unroll
            for (int r = 0; r < 4; ++r) {
                float a = acc[ct][r];
                if (ct < 4) { pS0[r] += a * sv[ct]; pD0[r] += a * dv[ct]; }
                else        { pS1[r] += a * sv[ct]; pD1[r] += a * dv[ct]; }
            }
        }
        #pragma unroll
        for (int m = 1; m < 16; m <<= 1) {
            #pragma unroll
            for (int r = 0; r < 4; ++r) {
                pS0[r] += __shfl_xor(pS0[r], m);
                pS1[r] += __shfl_xor(pS1[r], m);
                pD0[r] += __shfl_xor(pD0[r], m);
                pD1[r] += __shfl_xor(pD1[r], m);
            }
        }
        #pragma unroll
        for (int r = 0; r < 4; ++r) {
            int grow = brow + w * 16 + qr * 4 + r;
            if (grow < M) {
                if (col == 0) {
                    a_src[2 * grow + 0] = pS0[r];
                    a_src[2 * grow + 1] = pS1[r];
                    a_dst[2 * grow + 0] = pD0[r];
                    a_dst[2 * grow + 1] = pD1[r];
                }
                #pragma unroll
                for (int ct = 0; ct < 4; ++ct)
                    hb[(size_t)grow * 64 + ct * 16 + col] =
                        bf16pack(acc[ct][r], acc[ct + 4][r]);
            }
        }
    };

    int tile = blockIdx.x;
    if (tile >= T) return;
    float4 lr[8];
    LOAD(tile, lr);
    STORE(0, lr);
    __syncthreads();
    int cur = 0;
    for (;;) {
        int nxt = tile + stride;
        float4 nr[8];
        bool hasN = (nxt < T);
        if (hasN) LOAD(nxt, nr);              // issue loads for next tile
        COMPUTE(cur, tile);                   // overlap: MFMA+epilogue hide latency
        if (!hasN) break;
        STORE(cur ^ 1, nr);                   // waitcnt lands here
        __syncthreads();
        cur ^= 1;
        tile = nxt;
    }
}

// ---------------------------------------------------------------------------
// E: per-bucket counting sort + alpha/exp. One block per 256-node bucket:
// count -> prefix -> alpha/exp (a_dst LDS-staged, a_src L2 gather) ->
// rank-scatter final payload {src, half2 ex}; writes rowptr.
// ---------------------------------------------------------------------------
__global__ __launch_bounds__(256) void k_csr(const uint2* __restrict__ pA,
                                             const int* __restrict__ off,
                                             const int* __restrict__ bsum2,
                                             const float* __restrict__ a_src,
                                             const float* __restrict__ a_dst,
                                             int* __restrict__ rowptr,
                                             uint2* __restrict__ payload,
                                             int M, int E, int NB, int PB) {
    __shared__ int cnt[256];
    __shared__ int sc[256];
    __shared__ int cur[256];
    __shared__ float2 adl[256];
    int b = blockIdx.x, t = threadIdx.x;
    int n0 = b << BSH;
    int nloc = M - n0; if (nloc > 256) nloc = 256;

    size_t o0 = (size_t)b * PB;
    int s0 = off[o0] + bsum2[(int)(o0 >> 10)];
    int s1 = E;
    if (b + 1 < NB) {
        size_t o1 = (size_t)(b + 1) * PB;
        s1 = off[o1] + bsum2[(int)(o1 >> 10)];
    }
    cnt[t] = 0;
    if (t < nloc) adl[t] = ((const float2*)a_dst)[n0 + t];
    __syncthreads();

    for (int i = s0 + t; i < s1; i += 256)
        atomicAdd(&cnt[(pA[i].x >> 17) & BMSK], 1);
    __syncthreads();
    int c = cnt[t];
    sc[t] = c;
    __syncthreads();
    for (int o = 1; o < 256; o <<= 1) {
        int u = (t >= o) ? sc[t - o] : 0;
        __syncthreads();
        sc[t] += u;
        __syncthreads();
    }
    {
        int base = s0 + sc[t] - c;
        cur[t] = base;
        if (t < nloc) rowptr[n0 + t] = base;
    }
    if (b == NB - 1 && t == 0) rowptr[M] = E;
    __syncthreads();
    for (int i = s0 + t; i < s1; i += 256) {
        uint2 p = pA[i];
        int src = p.x & 0x1FFFF;
        int dl = (p.x >> 17) & BMSK;
        __half2 aeh = *reinterpret_cast<__half2*>(&p.y);
        float2 as = ((const float2*)a_src)[src];
        float2 ad = adl[dl];
        float al0 = as.x + ad.x + __low2float(aeh);
        al0 = al0 > 0.f ? al0 : NEG_SLOPE * al0;
        float al1 = as.y + ad.y + __high2float(aeh);
        al1 = al1 > 0.f ? al1 : NEG_SLOPE * al1;
        __half2 hx = __floats2half2_rn(__expf(al0), __expf(al1));
        int pos = atomicAdd(&cur[dl], 1);
        payload[pos] = make_uint2((unsigned)src, *reinterpret_cast<unsigned*>(&hx));
    }
}

// ---------------------------------------------------------------------------
// F: gather per node (wave per node, lane = channel). Payload tile staged in
// wave-private LDS -> uniform broadcast reads; src readfirstlane'd ->
// SGPR-base hb loads, 8 in flight. In-loop denominator; fused LN+ReLU.
// ---------------------------------------------------------------------------
__global__ __launch_bounds__(256) void k_gather(const uint2* __restrict__ payload,
                                                const int* __restrict__ rowptr,
                                                const unsigned* __restrict__ hb,
                                                const float* __restrict__ bias,
                                                const float* __restrict__ gamma,
                                                const float* __restrict__ beta,
                                                float* __restrict__ out, int M) {
    __shared__ uint2 stg[4][64];
    int w = threadIdx.x >> 6, lane = threadIdx.x & 63;
    int n = blockIdx.x * 4 + w;
    if (n >= M) return;
    int beg = rowptr[n], end = rowptr[n + 1];
    float acc0 = 0.f, acc1 = 0.f, pe0 = 0.f, pe1 = 0.f;

    for (int base = beg; base < end; base += 64) {
        int cnt = end - base; if (cnt > 64) cnt = 64;
        uint2 p = make_uint2(0u, 0u);
        if (lane < cnt) p = payload[base + lane];
        stg[w][lane] = p;
        {
            __half2 he = *reinterpret_cast<__half2*>(&p.y);
            pe0 += __low2float(he);
            pe1 += __high2float(he);
        }
        int j = 0;
        for (; j + 8 <= cnt; j += 8) {
            uint2 q0 = stg[w][j + 0], q1 = stg[w][j + 1];
            uint2 q2 = stg[w][j + 2], q3 = stg[w][j + 3];
            uint2 q4 = stg[w][j + 4], q5 = stg[w][j + 5];
            uint2 q6 = stg[w][j + 6], q7 = stg[w][j + 7];
            int s0 = __builtin_amdgcn_readfirstlane((int)q0.x);
            int s1 = __builtin_amdgcn_readfirstlane((int)q1.x);
            int s2 = __builtin_amdgcn_readfirstlane((int)q2.x);
            int s3 = __builtin_amdgcn_readfirstlane((int)q3.x);
            int s4 = __builtin_amdgcn_readfirstlane((int)q4.x);
            int s5 = __builtin_amdgcn_readfirstlane((int)q5.x);
            int s6 = __builtin_amdgcn_readfirstlane((int)q6.x);
            int s7 = __builtin_amdgcn_readfirstlane((int)q7.x);
            unsigned h0 = (hb + (size_t)s0 * 64)[lane];
            unsigned h1 = (hb + (size_t)s1 * 64)[lane];
            unsigned h2 = (hb + (size_t)s2 * 64)[lane];
            unsigned h3 = (hb + (size_t)s3 * 64)[lane];
            unsigned h4 = (hb + (size_t)s4 * 64)[lane];
            unsigned h5 = (hb + (size_t)s5 * 64)[lane];
            unsigned h6 = (hb + (size_t)s6 * 64)[lane];
            unsigned h7 = (hb + (size_t)s7 * 64)[lane];
            __half2 e0 = *reinterpret_cast<__half2*>(&q0.y);
            __half2 e1 = *reinterpret_cast<__half2*>(&q1.y);
            __half2 e2 = *reinterpret_cast<__half2*>(&q2.y);
            __half2 e3 = *reinterpret_cast<__half2*>(&q3.y);
            __half2 e4 = *reinterpret_cast<__half2*>(&q4.y);
            __half2 e5 = *reinterpret_cast<__half2*>(&q5.y);
            __half2 e6 = *reinterpret_cast<__half2*>(&q6.y);
            __half2 e7 = *reinterpret_cast<__half2*>(&q7.y);
            acc0 += __low2float(e0)  * __uint_as_float(h0 << 16);
            acc1 += __high2float(e0) * __uint_as_float(h0 & 0xffff0000u);
            acc0 += __low2float(e1)  * __uint_as_float(h1 << 16);
            acc1 += __high2float(e1) * __uint_as_float(h1 & 0xffff0000u);
            acc0 += __low2float(e2)  * __uint_as_float(h2 << 16);
            acc1 += __high2float(e2) * __uint_as_float(h2 & 0xffff0000u);
            acc0 += __low2float(e3)  * __uint_as_float(h3 << 16);
            acc1 += __high2float(e3) * __uint_as_float(h3 & 0xffff0000u);
            acc0 += __low2float(e4)  * __uint_as_float(h4 << 16);
            acc1 += __high2float(e4) * __uint_as_float(h4 & 0xffff0000u);
            acc0 += __low2float(e5)  * __uint_as_float(h5 << 16);
            acc1 += __high2float(e5) * __uint_as_float(h5 & 0xffff0000u);
            acc0 += __low2float(e6)  * __uint_as_float(h6 << 16);
            acc1 += __high2float(e6) * __uint_as_float(h6 & 0xffff0000u);
            acc0 += __low2float(e7)  * __uint_as_float(h7 << 16);
            acc1 += __high2float(e7) * __uint_as_float(h7 & 0xffff0000u);
        }
        for (; j + 4 <= cnt; j += 4) {
            uint2 q0 = stg[w][j + 0], q1 = stg[w][j + 1];
            uint2 q2 = stg[w][j + 2], q3 = stg[w][j + 3];
            int s0 = __builtin_amdgcn_readfirstlane((int)q0.x);
            int s1 = __builtin_amdgcn_readfirstlane((int)q1.x);
            int s2 = __builtin_amdgcn_readfirstlane((int)q2.x);
            int s3 = __builtin_amdgcn_readfirstlane((int)q3.x);
            unsigned h0 = (hb + (size_t)s0 * 64)[lane];
            unsigned h1 = (hb + (size_t)s1 * 64)[lane];
            unsigned h2 = (hb + (size_t)s2 * 64)[lane];
            unsigned h3 = (hb + (size_t)s3 * 64)[lane];
            __half2 e0 = *reinterpret_cast<__half2*>(&q0.y);
            __half2 e1 = *reinterpret_cast<__half2*>(&q1.y);
            __half2 e2 = *reinterpret_cast<__half2*>(&q2.y);
            __half2 e3 = *reinterpret_cast<__half2*>(&q3.y);
            acc0 += __low2float(e0)  * __uint_as_float(h0 << 16);
            acc1 += __high2float(e0) * __uint_as_float(h0 & 0xffff0000u);
            acc0 += __low2float(e1)  * __uint_as_float(h1 << 16);
            acc1 += __high2float(e1) * __uint_as_float(h1 & 0xffff0000u);
            acc0 += __low2float(e2)  * __uint_as_float(h2 << 16);
            acc1 += __high2float(e2) * __uint_as_float(h2 & 0xffff0000u);
            acc0 += __low2float(e3)  * __uint_as_float(h3 << 16);
            acc1 += __high2float(e3) * __uint_as_float(h3 & 0xffff0000u);
        }
        for (; j < cnt; ++j) {
            uint2 q0 = stg[w][j];
            int s0 = __builtin_amdgcn_readfirstlane((int)q0.x);
            unsigned h0 = (hb + (size_t)s0 * 64)[lane];
            __half2 e0 = *reinterpret_cast<__half2*>(&q0.y);
            acc0 += __low2float(e0)  * __uint_as_float(h0 << 16);
            acc1 += __high2float(e0) * __uint_as_float(h0 & 0xffff0000u);
        }
    }

    float d0 = pe0, d1 = pe1;
    #pragma unroll
    for (int m = 32; m; m >>= 1) {
        d0 += __shfl_xor(d0, m);
        d1 += __shfl_xor(d1, m);
    }

    float o = 0.5f * (acc0 / (d0 + 1e-16f) + acc1 / (d1 + 1e-16f)) + bias[lane];
    float mu = o;
    #pragma unroll
    for (int m = 32; m; m >>= 1) mu += __shfl_xor(mu, m);
    mu *= (1.f / 64.f);
    float c = o - mu;
    float v = c * c;
    #pragma unroll
    for (int m = 32; m; m >>= 1) v += __shfl_xor(v, m);
    v *= (1.f / 64.f);
    float y = c * rsqrtf(v + LN_EPS) * gamma[lane] + beta[lane];
    out[(size_t)n * OUT_C + lane] = fmaxf(y, 0.f);
}

// ---------------------------------------------------------------------------
extern "C" void kernel_launch(void* const* d_in, const int* in_sizes, int n_in,
                              void* d_out, int out_size, void* d_ws, size_t ws_size,
                              hipStream_t stream) {
    const float* x     = (const float*)d_in[0];
    const int*   ei    = (const int*)d_in[1];
    const float* ea    = (const float*)d_in[2];
    const float* W     = (const float*)d_in[3];
    const float* attS  = (const float*)d_in[4];
    const float* attD  = (const float*)d_in[5];
    const float* We    = (const float*)d_in[6];
    const float* attE  = (const float*)d_in[7];
    const float* bias  = (const float*)d_in[8];
    const float* gamma = (const float*)d_in[9];
    const float* beta  = (const float*)d_in[10];

    const int M  = in_sizes[0] / IN_C;        // 100000
    const int E  = in_sizes[1] / 2;           // 1600000
    const int NB = (M + BMSK) >> BSH;         // 391 buckets (256 nodes)
    const int PB = (E + CHUNK - 1) / CHUNK;   // 391 partition chunks
    const int nS = NB * PB;                   // 152881 offsets
    const int nb2 = (nS + 1023) / 1024;       // 150 scan blocks
    const int T  = (M + 63) / 64;             // 1563 gemm tiles

    char* ws = (char*)d_ws;
    size_t woff = 0;
    auto alloc = [&](size_t bytes) -> void* {
        void* p = ws + woff;
        woff += (bytes + 255) & ~(size_t)255;
        return p;
    };
    unsigned*       hb     = (unsigned*)      alloc((size_t)M * 64 * 4);
    float*          a_src  = (float*)         alloc((size_t)M * 2 * 4);
    float*          a_dst  = (float*)         alloc((size_t)M * 2 * 4);
    int*            off    = (int*)           alloc((size_t)nS * 4);
    int*            bsum   = (int*)           alloc((size_t)nb2 * 4);
    int*            bsum2  = (int*)           alloc((size_t)nb2 * 4);
    int*            rowptr = (int*)           alloc((size_t)(M + 1) * 4);
    uint2*          pA     = (uint2*)         alloc((size_t)E * 8);
    uint2*          payload= (uint2*)         alloc((size_t)E * 8);
    unsigned short* WbfT   = (unsigned short*)alloc(128 * 128 * 2);
    float*          V      = (float*)         alloc(32);

    k_pre<<<9 + PB, 256, 0, stream>>>(W, We, attE, ei + E, WbfT, V, off, E, NB, PB);
    k_scan<<<nb2, 256, 0, stream>>>(off, bsum, nS);
    k_part<<<PB, 256, 0, stream>>>(ei, ea, V, off, bsum, bsum2, pA, E, NB, PB, nb2);
    k_gemm<<<NGB, 256, 0, stream>>>(x, WbfT, attS, attD, hb, a_src, a_dst, M, T, NGB);
    k_csr<<<NB, 256, 0, stream>>>(pA, off, bsum2, a_src, a_dst, rowptr, payload,
                                  M, E, NB, PB);
    k_gather<<<(M + 3) / 4, 256, 0, stream>>>(payload, rowptr, hb, bias, gamma, beta,
                                              (float*)d_out, M);
}

// Round 16
// 143.771 us; speedup vs baseline: 1.0772x; 1.0772x over previous
//
#include <hip/hip_runtime.h>
#include <hip/hip_fp16.h>
#include <math.h>

#define IN_C 128
#define HC   128
#define OUT_C 64
#define NEG_SLOPE 0.2f
#define LN_EPS 1e-5f
#define CHUNK 4096        // edges per partition chunk (391 chunks)
#define BSH   8           // bucket shift: 256 nodes per bucket
#define BMSK  255
#define NBMAX 512         // max buckets (dst>>8; M<=131072)
#define NB2MAX 1024       // max scan blocks (4/thread inline scan)

typedef __attribute__((ext_vector_type(8))) _Float16 f16x8;
typedef __attribute__((ext_vector_type(4))) float f32x4;

// pack two floats to fp16 pair in a uint (a=low, b=high), round-nearest
__device__ inline unsigned h2pack(float a, float b) {
    __half2 h = __floats2half2_rn(a, b);
    return *reinterpret_cast<unsigned*>(&h);
}

// ---------------------------------------------------------------------------
// A: blocks 0..7 WhT[col][k]=fp16(W[k][col]); block 8 folds V; blocks 9..
// per-chunk LDS histogram over NB buckets -> off[bucket][chunk] raw counts.
// ---------------------------------------------------------------------------
__global__ __launch_bounds__(256) void k_pre(const float* __restrict__ W,
                                             const float* __restrict__ W_edge,
                                             const float* __restrict__ att_edge,
                                             const int* __restrict__ ei_dst,
                                             unsigned short* __restrict__ WhT,
                                             float* __restrict__ V,
                                             int* __restrict__ off,
                                             int E, int NB, int PB) {
    __shared__ int hist[NBMAX];
    int b = blockIdx.x, t = threadIdx.x;
    if (b < 8) {
        #pragma unroll
        for (int i = 0; i < 8; ++i) {
            int idx = b * 2048 + i * 256 + t;      // 0..16383
            int k = idx >> 7, col = idx & 127;
            __half hh = __float2half_rn(W[idx]);
            WhT[col * 128 + k] = *reinterpret_cast<unsigned short*>(&hh);
        }
        return;
    }
    if (b == 8) {
        if (t < 8) {
            int d = t >> 1, h = t & 1;
            float s = 0.f;
            for (int c = 0; c < 64; ++c)
                s += W_edge[d * HC + h * 64 + c] * att_edge[h * 64 + c];
            V[d * 2 + h] = s;
        }
        return;
    }
    int pb = b - 9;
    for (int i = t; i < NB; i += 256) hist[i] = 0;
    __syncthreads();
    int base = pb * CHUNK;
    int lim = E - base; if (lim > CHUNK) lim = CHUNK;
    if (lim == CHUNK) {                       // 16 edges/thread, 4x int4
        #pragma unroll
        for (int u = 0; u < 4; ++u) {
            int4 v = *(const int4*)&ei_dst[base + u * 1024 + t * 4];
            atomicAdd(&hist[v.x >> BSH], 1);
            atomicAdd(&hist[v.y >> BSH], 1);
            atomicAdd(&hist[v.z >> BSH], 1);
            atomicAdd(&hist[v.w >> BSH], 1);
        }
    } else {
        for (int i = t; i < lim; i += 256)
            atomicAdd(&hist[ei_dst[base + i] >> BSH], 1);
    }
    __syncthreads();
    for (int i = t; i < NB; i += 256)
        off[(size_t)i * PB + pb] = hist[i];
}

// ---------------------------------------------------------------------------
// B: scan1 of off[] (1024 elems/block, in-place exclusive; raw bsum out)
// ---------------------------------------------------------------------------
__global__ __launch_bounds__(256) void k_scan(int* __restrict__ off,
                                              int* __restrict__ bsum, int nS) {
    __shared__ int sm[256];
    int t = threadIdx.x;
    int base = blockIdx.x * 1024 + t * 4;
    int v0 = 0, v1 = 0, v2 = 0, v3 = 0;
    if (base + 0 < nS) v0 = off[base + 0];
    if (base + 1 < nS) v1 = off[base + 1];
    if (base + 2 < nS) v2 = off[base + 2];
    if (base + 3 < nS) v3 = off[base + 3];
    int s = v0 + v1 + v2 + v3;
    sm[t] = s;
    __syncthreads();
    for (int o = 1; o < 256; o <<= 1) {
        int u = (t >= o) ? sm[t - o] : 0;
        __syncthreads();
        sm[t] += u;
        __syncthreads();
    }
    int excl = sm[t] - s;
    if (base + 0 < nS) off[base + 0] = excl;
    if (base + 1 < nS) off[base + 1] = excl + v0;
    if (base + 2 < nS) off[base + 2] = excl + v0 + v1;
    if (base + 3 < nS) off[base + 3] = excl + v0 + v1 + v2;
    if (t == 255) bsum[blockIdx.x] = sm[255];
}

// ---------------------------------------------------------------------------
// inline exclusive scan of bsum[0..nb2) into bs[] (nb2 <= 1024, 4/thread)
// ---------------------------------------------------------------------------
__device__ inline void scan_bsum(const int* __restrict__ bsum, int nb2,
                                 int* bs, int* sm, int t) {
    int v0 = (4 * t + 0 < nb2) ? bsum[4 * t + 0] : 0;
    int v1 = (4 * t + 1 < nb2) ? bsum[4 * t + 1] : 0;
    int v2 = (4 * t + 2 < nb2) ? bsum[4 * t + 2] : 0;
    int v3 = (4 * t + 3 < nb2) ? bsum[4 * t + 3] : 0;
    int s = v0 + v1 + v2 + v3;
    sm[t] = s;
    __syncthreads();
    for (int o = 1; o < 256; o <<= 1) {
        int u = (t >= o) ? sm[t - o] : 0;
        __syncthreads();
        sm[t] += u;
        __syncthreads();
    }
    int excl = sm[t] - s;
    bs[4 * t + 0] = excl;
    bs[4 * t + 1] = excl + v0;
    bs[4 * t + 2] = excl + v0 + v1;
    bs[4 * t + 3] = excl + v0 + v1 + v2;
    __syncthreads();
}

// ---------------------------------------------------------------------------
// C fused: per 5 consecutive blocks, 4 GEMM + 1 partition.
//   r=bid%5<4 : GEMM block gid=g*4+r (x@W fp16 MFMA, logits, fp16 pack)
//   r==4      : partition chunk pid=g — ae=ea·V only, writes
//               pA={src|dl<<17, half2(ae0,ae1)}; pid 0 publishes bsum2.
// ---------------------------------------------------------------------------
__global__ __launch_bounds__(256) void k_fused(
        const float* __restrict__ x,
        const unsigned short* __restrict__ WhT,
        const float* __restrict__ attS, const float* __restrict__ attD,
        unsigned* __restrict__ hb,
        float* __restrict__ a_src, float* __restrict__ a_dst, int M,
        const int* __restrict__ ei, const float* __restrict__ ea,
        const float* __restrict__ V,
        const int* __restrict__ off, const int* __restrict__ bsum,
        int* __restrict__ bsum2, uint2* __restrict__ pA,
        int E, int NB, int PB, int nb2, int GB) {
    __shared__ unsigned xb[64 * 64];          // 16 KB; part branch aliases it
    const int t = threadIdx.x;
    const int bid = blockIdx.x;
    const int r5 = bid % 5, g5 = bid / 5;

    if (r5 == 4) {                            // ---- partition branch ----
        int* cur = (int*)xb;                  // [NBMAX]
        int* bs  = (int*)xb + NBMAX;          // [NB2MAX]
        int* sm  = (int*)xb + NBMAX + NB2MAX; // [256]
        int pb = g5;
        scan_bsum(bsum, nb2, bs, sm, t);
        if (pb == 0)
            for (int i = t; i < nb2; i += 256) bsum2[i] = bs[i];
        for (int i = t; i < NB; i += 256) {
            size_t oi = (size_t)i * PB + pb;
            cur[i] = off[oi] + bs[(int)(oi >> 10)];
        }
        __syncthreads();
        float v0 = V[0], v1 = V[1], v2 = V[2], v3 = V[3];
        float v4 = V[4], v5 = V[5], v6 = V[6], v7 = V[7];
        int base = pb * CHUNK;
        int lim = E - base; if (lim > CHUNK) lim = CHUNK;
        if (lim == CHUNK) {                   // 2 batches x 8 edges/thread
            #pragma unroll
            for (int h = 0; h < 2; ++h) {
                int e0 = base + h * 2048 + t;
                int sA[8], dA[8];
                #pragma unroll
                for (int k = 0; k < 8; ++k) {
                    sA[k] = ei[e0 + k * 256];
                    dA[k] = ei[E + e0 + k * 256];
                }
                float4 aA[8];
                #pragma unroll
                for (int k = 0; k < 8; ++k)
                    aA[k] = ((const float4*)ea)[e0 + k * 256];
                #pragma unroll
                for (int k = 0; k < 8; ++k) {
                    float ae0 = aA[k].x * v0 + aA[k].y * v2 + aA[k].z * v4 + aA[k].w * v6;
                    float ae1 = aA[k].x * v1 + aA[k].y * v3 + aA[k].z * v5 + aA[k].w * v7;
                    int slot = atomicAdd(&cur[dA[k] >> BSH], 1);
                    pA[slot] = make_uint2(
                        (unsigned)sA[k] | ((unsigned)(dA[k] & BMSK) << 17),
                        h2pack(ae0, ae1));
                }
            }
        } else {
            for (int i = t; i < lim; i += 256) {
                int e = base + i;
                int s = ei[e], d = ei[E + e];
                float4 a = ((const float4*)ea)[e];
                float ae0 = a.x * v0 + a.y * v2 + a.z * v4 + a.w * v6;
                float ae1 = a.x * v1 + a.y * v3 + a.z * v5 + a.w * v7;
                int slot = atomicAdd(&cur[d >> BSH], 1);
                pA[slot] = make_uint2((unsigned)s | ((unsigned)(d & BMSK) << 17),
                                      h2pack(ae0, ae1));
            }
        }
        return;
    }

    // ---- GEMM branch (fp16 MFMA) ----
    const int gid = g5 * 4 + r5;
    if (gid >= GB) return;
    const int brow = gid * 64;
    const float4* x4 = (const float4*)x;
    #pragma unroll
    for (int i = 0; i < 8; ++i) {
        int idx = i * 256 + t;
        int row = idx >> 5, c4 = idx & 31;
        float4 v = make_float4(0.f, 0.f, 0.f, 0.f);
        if (brow + row < M) v = x4[(size_t)(brow + row) * 32 + c4];
        unsigned lo = h2pack(v.x, v.y), hi = h2pack(v.z, v.w);
        int byte = row * 256 + ((c4 * 8) ^ ((row & 7) << 4));
        *(uint2*)((char*)xb + byte) = make_uint2(lo, hi);
    }
    __syncthreads();

    const int w = t >> 6, lane = t & 63;
    const int col = lane & 15, qr = lane >> 4;
    f32x4 acc[8];
    #pragma unroll
    for (int ct = 0; ct < 8; ++ct) acc[ct] = (f32x4){0.f, 0.f, 0.f, 0.f};

    const int arow = w * 16 + col;
    #pragma unroll
    for (int ks = 0; ks < 4; ++ks) {
        int abyte = arow * 256 + ((ks * 64 + qr * 16) ^ ((arow & 7) << 4));
        f16x8 af = *(const f16x8*)((const char*)xb + abyte);
        #pragma unroll
        for (int ct = 0; ct < 8; ++ct) {
            f16x8 bfr = *(const f16x8*)&WhT[(size_t)(ct * 16 + col) * 128 + ks * 32 + qr * 8];
            acc[ct] = __builtin_amdgcn_mfma_f32_16x16x32_f16(af, bfr, acc[ct], 0, 0, 0);
        }
    }

    float pS0[4], pS1[4], pD0[4], pD1[4];
    #pragma unroll
    for (int r = 0; r < 4; ++r) { pS0[r] = pS1[r] = pD0[r] = pD1[r] = 0.f; }
    #pragma unroll
    for (int ct = 0; ct < 8; ++ct) {
        float s = attS[ct * 16 + col], d = attD[ct * 16 + col];
        #pragma unroll
        for (int r = 0; r < 4; ++r) {
            float a = acc[ct][r];
            if (ct < 4) { pS0[r] += a * s; pD0[r] += a * d; }
            else        { pS1[r] += a * s; pD1[r] += a * d; }
        }
    }
    #pragma unroll
    for (int m = 1; m < 16; m <<= 1) {
        #pragma unroll
        for (int r = 0; r < 4; ++r) {
            pS0[r] += __shfl_xor(pS0[r], m);
            pS1[r] += __shfl_xor(pS1[r], m);
            pD0[r] += __shfl_xor(pD0[r], m);
            pD1[r] += __shfl_xor(pD1[r], m);
        }
    }
    #pragma unroll
    for (int r = 0; r < 4; ++r) {
        int grow = brow + w * 16 + qr * 4 + r;
        if (grow < M) {
            if (col == 0) {
                a_src[2 * grow + 0] = pS0[r];
                a_src[2 * grow + 1] = pS1[r];
                a_dst[2 * grow + 0] = pD0[r];
                a_dst[2 * grow + 1] = pD1[r];
            }
            #pragma unroll
            for (int ct = 0; ct < 4; ++ct)
                hb[(size_t)grow * 64 + ct * 16 + col] =
                    h2pack(acc[ct][r], acc[ct + 4][r]);
        }
    }
}

// ---------------------------------------------------------------------------
// D: per-bucket counting sort + alpha/exp. One block per 256-node bucket:
// count -> prefix -> alpha/exp (a_dst LDS-staged, a_src L2 gather) ->
// rank-scatter final payload {src, half2 ex}; writes rowptr.
// ---------------------------------------------------------------------------
__global__ __launch_bounds__(256) void k_csr(const uint2* __restrict__ pA,
                                             const int* __restrict__ off,
                                             const int* __restrict__ bsum2,
                                             const float* __restrict__ a_src,
                                             const float* __restrict__ a_dst,
                                             int* __restrict__ rowptr,
                                             uint2* __restrict__ payload,
                                             int M, int E, int NB, int PB) {
    __shared__ int cnt[256];
    __shared__ int sc[256];
    __shared__ int cur[256];
    __shared__ float2 adl[256];
    int b = blockIdx.x, t = threadIdx.x;
    int n0 = b << BSH;
    int nloc = M - n0; if (nloc > 256) nloc = 256;

    size_t o0 = (size_t)b * PB;
    int s0 = off[o0] + bsum2[(int)(o0 >> 10)];
    int s1 = E;
    if (b + 1 < NB) {
        size_t o1 = (size_t)(b + 1) * PB;
        s1 = off[o1] + bsum2[(int)(o1 >> 10)];
    }
    cnt[t] = 0;
    if (t < nloc) adl[t] = ((const float2*)a_dst)[n0 + t];
    __syncthreads();

    for (int i = s0 + t; i < s1; i += 256)
        atomicAdd(&cnt[(pA[i].x >> 17) & BMSK], 1);
    __syncthreads();
    int c = cnt[t];
    sc[t] = c;
    __syncthreads();
    for (int o = 1; o < 256; o <<= 1) {
        int u = (t >= o) ? sc[t - o] : 0;
        __syncthreads();
        sc[t] += u;
        __syncthreads();
    }
    {
        int base = s0 + sc[t] - c;
        cur[t] = base;
        if (t < nloc) rowptr[n0 + t] = base;
    }
    if (b == NB - 1 && t == 0) rowptr[M] = E;
    __syncthreads();
    for (int i = s0 + t; i < s1; i += 256) {
        uint2 p = pA[i];
        int src = p.x & 0x1FFFF;
        int dl = (p.x >> 17) & BMSK;
        __half2 aeh = *reinterpret_cast<__half2*>(&p.y);
        float2 as = ((const float2*)a_src)[src];
        float2 ad = adl[dl];
        float al0 = as.x + ad.x + __low2float(aeh);
        al0 = al0 > 0.f ? al0 : NEG_SLOPE * al0;
        float al1 = as.y + ad.y + __high2float(aeh);
        al1 = al1 > 0.f ? al1 : NEG_SLOPE * al1;
        int pos = atomicAdd(&cur[dl], 1);
        payload[pos] = make_uint2((unsigned)src,
                                  h2pack(__expf(al0), __expf(al1)));
    }
}

// ---------------------------------------------------------------------------
// E: gather per node (wave per node, lane = channel). Payload tile staged in
// wave-private LDS -> uniform broadcast reads; src readfirstlane'd ->
// SGPR-base hb loads (fp16 pairs), 8 in flight. In-loop denominator;
// fused head-mean + bias + LayerNorm + ReLU.
// ---------------------------------------------------------------------------
__global__ __launch_bounds__(256) void k_gather(const uint2* __restrict__ payload,
                                                const int* __restrict__ rowptr,
                                                const unsigned* __restrict__ hb,
                                                const float* __restrict__ bias,
                                                const float* __restrict__ gamma,
                                                const float* __restrict__ beta,
                                                float* __restrict__ out, int M) {
    __shared__ uint2 stg[4][64];
    int w = threadIdx.x >> 6, lane = threadIdx.x & 63;
    int n = blockIdx.x * 4 + w;
    if (n >= M) return;
    int beg = rowptr[n], end = rowptr[n + 1];
    float acc0 = 0.f, acc1 = 0.f, pe0 = 0.f, pe1 = 0.f;

    for (int base = beg; base < end; base += 64) {
        int cnt = end - base; if (cnt > 64) cnt = 64;
        uint2 p = make_uint2(0u, 0u);
        if (lane < cnt) p = payload[base + lane];
        stg[w][lane] = p;
        {
            __half2 he = *reinterpret_cast<__half2*>(&p.y);
            pe0 += __low2float(he);
            pe1 += __high2float(he);
        }
        int j = 0;
        for (; j + 8 <= cnt; j += 8) {
            uint2 q0 = stg[w][j + 0], q1 = stg[w][j + 1];
            uint2 q2 = stg[w][j + 2], q3 = stg[w][j + 3];
            uint2 q4 = stg[w][j + 4], q5 = stg[w][j + 5];
            uint2 q6 = stg[w][j + 6], q7 = stg[w][j + 7];
            int s0 = __builtin_amdgcn_readfirstlane((int)q0.x);
            int s1 = __builtin_amdgcn_readfirstlane((int)q1.x);
            int s2 = __builtin_amdgcn_readfirstlane((int)q2.x);
            int s3 = __builtin_amdgcn_readfirstlane((int)q3.x);
            int s4 = __builtin_amdgcn_readfirstlane((int)q4.x);
            int s5 = __builtin_amdgcn_readfirstlane((int)q5.x);
            int s6 = __builtin_amdgcn_readfirstlane((int)q6.x);
            int s7 = __builtin_amdgcn_readfirstlane((int)q7.x);
            unsigned h0 = (hb + (size_t)s0 * 64)[lane];
            unsigned h1 = (hb + (size_t)s1 * 64)[lane];
            unsigned h2 = (hb + (size_t)s2 * 64)[lane];
            unsigned h3 = (hb + (size_t)s3 * 64)[lane];
            unsigned h4 = (hb + (size_t)s4 * 64)[lane];
            unsigned h5 = (hb + (size_t)s5 * 64)[lane];
            unsigned h6 = (hb + (size_t)s6 * 64)[lane];
            unsigned h7 = (hb + (size_t)s7 * 64)[lane];
            __half2 e0 = *reinterpret_cast<__half2*>(&q0.y);
            __half2 e1 = *reinterpret_cast<__half2*>(&q1.y);
            __half2 e2 = *reinterpret_cast<__half2*>(&q2.y);
            __half2 e3 = *reinterpret_cast<__half2*>(&q3.y);
            __half2 e4 = *reinterpret_cast<__half2*>(&q4.y);
            __half2 e5 = *reinterpret_cast<__half2*>(&q5.y);
            __half2 e6 = *reinterpret_cast<__half2*>(&q6.y);
            __half2 e7 = *reinterpret_cast<__half2*>(&q7.y);
            __half2 g0 = *reinterpret_cast<__half2*>(&h0);
            __half2 g1 = *reinterpret_cast<__half2*>(&h1);
            __half2 g2 = *reinterpret_cast<__half2*>(&h2);
            __half2 g3 = *reinterpret_cast<__half2*>(&h3);
            __half2 g4 = *reinterpret_cast<__half2*>(&h4);
            __half2 g5 = *reinterpret_cast<__half2*>(&h5);
            __half2 g6 = *reinterpret_cast<__half2*>(&h6);
            __half2 g7 = *reinterpret_cast<__half2*>(&h7);
            acc0 += __low2float(e0)  * __low2float(g0);
            acc1 += __high2float(e0) * __high2float(g0);
            acc0 += __low2float(e1)  * __low2float(g1);
            acc1 += __high2float(e1) * __high2float(g1);
            acc0 += __low2float(e2)  * __low2float(g2);
            acc1 += __high2float(e2) * __high2float(g2);
            acc0 += __low2float(e3)  * __low2float(g3);
            acc1 += __high2float(e3) * __high2float(g3);
            acc0 += __low2float(e4)  * __low2float(g4);
            acc1 += __high2float(e4) * __high2float(g4);
            acc0 += __low2float(e5)  * __low2float(g5);
            acc1 += __high2float(e5) * __high2float(g5);
            acc0 += __low2float(e6)  * __low2float(g6);
            acc1 += __high2float(e6) * __high2float(g6);
            acc0 += __low2float(e7)  * __low2float(g7);
            acc1 += __high2float(e7) * __high2float(g7);
        }
        for (; j + 4 <= cnt; j += 4) {
            uint2 q0 = stg[w][j + 0], q1 = stg[w][j + 1];
            uint2 q2 = stg[w][j + 2], q3 = stg[w][j + 3];
            int s0 = __builtin_amdgcn_readfirstlane((int)q0.x);
            int s1 = __builtin_amdgcn_readfirstlane((int)q1.x);
            int s2 = __builtin_amdgcn_readfirstlane((int)q2.x);
            int s3 = __builtin_amdgcn_readfirstlane((int)q3.x);
            unsigned h0 = (hb + (size_t)s0 * 64)[lane];
            unsigned h1 = (hb + (size_t)s1 * 64)[lane];
            unsigned h2 = (hb + (size_t)s2 * 64)[lane];
            unsigned h3 = (hb + (size_t)s3 * 64)[lane];
            __half2 e0 = *reinterpret_cast<__half2*>(&q0.y);
            __half2 e1 = *reinterpret_cast<__half2*>(&q1.y);
            __half2 e2 = *reinterpret_cast<__half2*>(&q2.y);
            __half2 e3 = *reinterpret_cast<__half2*>(&q3.y);
            __half2 g0 = *reinterpret_cast<__half2*>(&h0);
            __half2 g1 = *reinterpret_cast<__half2*>(&h1);
            __half2 g2 = *reinterpret_cast<__half2*>(&h2);
            __half2 g3 = *reinterpret_cast<__half2*>(&h3);
            acc0 += __low2float(e0)  * __low2float(g0);
            acc1 += __high2float(e0) * __high2float(g0);
            acc0 += __low2float(e1)  * __low2float(g1);
            acc1 += __high2float(e1) * __high2float(g1);
            acc0 += __low2float(e2)  * __low2float(g2);
            acc1 += __high2float(e2) * __high2float(g2);
            acc0 += __low2float(e3)  * __low2float(g3);
            acc1 += __high2float(e3) * __high2float(g3);
        }
        for (; j < cnt; ++j) {
            uint2 q0 = stg[w][j];
            int s0 = __builtin_amdgcn_readfirstlane((int)q0.x);
            unsigned h0 = (hb + (size_t)s0 * 64)[lane];
            __half2 e0 = *reinterpret_cast<__half2*>(&q0.y);
            __half2 g0 = *reinterpret_cast<__half2*>(&h0);
            acc0 += __low2float(e0)  * __low2float(g0);
            acc1 += __high2float(e0) * __high2float(g0);
        }
    }

    float d0 = pe0, d1 = pe1;
    #pragma unroll
    for (int m = 32; m; m >>= 1) {
        d0 += __shfl_xor(d0, m);
        d1 += __shfl_xor(d1, m);
    }

    float o = 0.5f * (acc0 / (d0 + 1e-16f) + acc1 / (d1 + 1e-16f)) + bias[lane];
    float mu = o;
    #pragma unroll
    for (int m = 32; m; m >>= 1) mu += __shfl_xor(mu, m);
    mu *= (1.f / 64.f);
    float c = o - mu;
    float v = c * c;
    #pragma unroll
    for (int m = 32; m; m >>= 1) v += __shfl_xor(v, m);
    v *= (1.f / 64.f);
    float y = c * rsqrtf(v + LN_EPS) * gamma[lane] + beta[lane];
    out[(size_t)n * OUT_C + lane] = fmaxf(y, 0.f);
}

// ---------------------------------------------------------------------------
extern "C" void kernel_launch(void* const* d_in, const int* in_sizes, int n_in,
                              void* d_out, int out_size, void* d_ws, size_t ws_size,
                              hipStream_t stream) {
    const float* x     = (const float*)d_in[0];
    const int*   ei    = (const int*)d_in[1];
    const float* ea    = (const float*)d_in[2];
    const float* W     = (const float*)d_in[3];
    const float* attS  = (const float*)d_in[4];
    const float* attD  = (const float*)d_in[5];
    const float* We    = (const float*)d_in[6];
    const float* attE  = (const float*)d_in[7];
    const float* bias  = (const float*)d_in[8];
    const float* gamma = (const float*)d_in[9];
    const float* beta  = (const float*)d_in[10];

    const int M  = in_sizes[0] / IN_C;        // 100000
    const int E  = in_sizes[1] / 2;           // 1600000
    const int NB = (M + BMSK) >> BSH;         // 391 buckets (256 nodes)
    const int PB = (E + CHUNK - 1) / CHUNK;   // 391 partition chunks
    const int nS = NB * PB;                   // 152881 offsets
    const int nb2 = (nS + 1023) / 1024;       // 150 scan blocks
    const int GB = (M + 63) / 64;             // 1563 gemm blocks

    char* ws = (char*)d_ws;
    size_t woff = 0;
    auto alloc = [&](size_t bytes) -> void* {
        void* p = ws + woff;
        woff += (bytes + 255) & ~(size_t)255;
        return p;
    };
    unsigned*       hb     = (unsigned*)      alloc((size_t)M * 64 * 4);
    float*          a_src  = (float*)         alloc((size_t)M * 2 * 4);
    float*          a_dst  = (float*)         alloc((size_t)M * 2 * 4);
    int*            off    = (int*)           alloc((size_t)nS * 4);
    int*            bsum   = (int*)           alloc((size_t)nb2 * 4);
    int*            bsum2  = (int*)           alloc((size_t)nb2 * 4);
    int*            rowptr = (int*)           alloc((size_t)(M + 1) * 4);
    uint2*          pA     = (uint2*)         alloc((size_t)E * 8);
    uint2*          payload= (uint2*)         alloc((size_t)E * 8);
    unsigned short* WhT    = (unsigned short*)alloc(128 * 128 * 2);
    float*          V      = (float*)         alloc(32);

    k_pre<<<9 + PB, 256, 0, stream>>>(W, We, attE, ei + E, WhT, V, off, E, NB, PB);
    k_scan<<<nb2, 256, 0, stream>>>(off, bsum, nS);
    k_fused<<<5 * PB, 256, 0, stream>>>(x, WhT, attS, attD, hb, a_src, a_dst, M,
                                        ei, ea, V, off, bsum, bsum2, pA,
                                        E, NB, PB, nb2, GB);
    k_csr<<<NB, 256, 0, stream>>>(pA, off, bsum2, a_src, a_dst, rowptr, payload,
                                  M, E, NB, PB);
    k_gather<<<(M + 3) / 4, 256, 0, stream>>>(payload, rowptr, hb, bias, gamma, beta,
                                              (float*)d_out, M);
}